// Round 2
// baseline (373.366 us; speedup 1.0000x reference)
//
#include <hip/hip_runtime.h>
#include <hip/hip_bf16.h>
#include <cstdint>

#define DEV __device__ __forceinline__

typedef float f32x4 __attribute__((ext_vector_type(4)));
typedef __bf16 bf16x8 __attribute__((ext_vector_type(8)));
typedef unsigned short u16;
typedef u16 u16x8 __attribute__((ext_vector_type(8)));
typedef u16 u16x4 __attribute__((ext_vector_type(4)));

DEV u16 f2bf(float f) {
  union { float f; uint32_t u; } x{f};
  uint32_t r = x.u + 0x7FFFu + ((x.u >> 16) & 1u);
  return (u16)(r >> 16);
}

DEV void gl_lds16(const u16* g, u16* l) {
  __builtin_amdgcn_global_load_lds((const __attribute__((address_space(1))) void*)g,
                                   (__attribute__((address_space(3))) void*)l, 16, 0, 0);
}

// ---------------- f32 -> bf16 convert ----------------
__global__ __launch_bounds__(256) void k_cvt(const float* __restrict__ s,
                                             u16* __restrict__ d, int n) {
  int step = gridDim.x * blockDim.x * 4;
  for (int i = (blockIdx.x * blockDim.x + threadIdx.x) * 4; i < n; i += step) {
    float4 v = *reinterpret_cast<const float4*>(s + i);
    u16x4 o;
    o[0] = f2bf(v.x); o[1] = f2bf(v.y); o[2] = f2bf(v.z); o[3] = f2bf(v.w);
    *reinterpret_cast<u16x4*>(d + i) = o;
  }
}

// ---------------- GEMM: C[M,N] = A[M,K] @ B[N,K]^T (+bias, epilogue) -------
// MODE 0: bf16 out = acc+bias ; MODE 1: bf16 out = relu(acc+bias)
// MODE 2: f32 out = acc+bias+res
template <int MODE>
DEV void gemm_core(const u16* __restrict__ A, const u16* __restrict__ B,
                   const float* __restrict__ bias, const float* __restrict__ res,
                   void* __restrict__ C, int N, int K, int m0, int n0) {
  __shared__ u16 sA[2][128 * 32];
  __shared__ u16 sB[2][128 * 32];
  const int tid = threadIdx.x;
  const int w = tid >> 6, l = tid & 63;
  const int lr = l & 15, lg = l >> 4;
  const int wr = (w >> 1) * 64, wc = (w & 1) * 64;

  f32x4 acc[4][4] = {};

  const int nt = K >> 5;
  const int sr = w * 16 + (l >> 2);  // staging row (within 64-row half)
  const int sc = (l & 3) * 8;        // staging col (elements)

  auto stage = [&](int buf, int t) {
    const u16* ga = A + (size_t)(m0 + sr) * K + t * 32 + sc;
    const u16* gb = B + (size_t)(n0 + sr) * K + t * 32 + sc;
    gl_lds16(ga, &sA[buf][w * 512]);
    gl_lds16(ga + (size_t)64 * K, &sA[buf][2048 + w * 512]);
    gl_lds16(gb, &sB[buf][w * 512]);
    gl_lds16(gb + (size_t)64 * K, &sB[buf][2048 + w * 512]);
  };

  auto compute = [&](int buf) {
    bf16x8 af[4], bfr[4];
#pragma unroll
    for (int mf = 0; mf < 4; ++mf)
      af[mf] = *(const bf16x8*)&sA[buf][(wr + mf * 16 + lr) * 32 + lg * 8];
#pragma unroll
    for (int nf = 0; nf < 4; ++nf)
      bfr[nf] = *(const bf16x8*)&sB[buf][(wc + nf * 16 + lr) * 32 + lg * 8];
#pragma unroll
    for (int mf = 0; mf < 4; ++mf)
#pragma unroll
      for (int nf = 0; nf < 4; ++nf)
        acc[mf][nf] = __builtin_amdgcn_mfma_f32_16x16x32_bf16(af[mf], bfr[nf],
                                                              acc[mf][nf], 0, 0, 0);
  };

  stage(0, 0);
  __syncthreads();
  int cur = 0;
  for (int t = 0; t < nt - 1; ++t) {
    stage(cur ^ 1, t + 1);
    compute(cur);
    __syncthreads();
    cur ^= 1;
  }
  compute(cur);

#pragma unroll
  for (int nf = 0; nf < 4; ++nf) {
    const int col = n0 + wc + nf * 16 + lr;
    const float bv = bias[col];
#pragma unroll
    for (int mf = 0; mf < 4; ++mf) {
      const int row0 = m0 + wr + mf * 16 + lg * 4;
#pragma unroll
      for (int r = 0; r < 4; ++r) {
        float v = acc[mf][nf][r] + bv;
        if (MODE == 1) v = fmaxf(v, 0.0f);
        const size_t idx = (size_t)(row0 + r) * N + col;
        if (MODE == 2) ((float*)C)[idx] = v + res[idx];
        else ((u16*)C)[idx] = f2bf(v);
      }
    }
  }
}

template <int MODE>
__global__ __launch_bounds__(256) void k_gemm(const u16* __restrict__ A,
                                              const u16* __restrict__ B,
                                              const float* __restrict__ bias,
                                              const float* __restrict__ res,
                                              void* __restrict__ C, int N, int K) {
  gemm_core<MODE>(A, B, bias, res, C, N, K, blockIdx.x * 128, blockIdx.y * 128);
}

__global__ __launch_bounds__(256) void k_gemm_qkv(
    const u16* __restrict__ A, const u16* __restrict__ B0, const u16* __restrict__ B1,
    const u16* __restrict__ B2, const float* __restrict__ c0,
    const float* __restrict__ c1, const float* __restrict__ c2,
    u16* __restrict__ O0, u16* __restrict__ O1, u16* __restrict__ O2) {
  const int z = blockIdx.z;
  const u16* B = (z == 0) ? B0 : (z == 1) ? B1 : B2;
  const float* bias = (z == 0) ? c0 : (z == 1) ? c1 : c2;
  u16* O = (z == 0) ? O0 : (z == 1) ? O1 : O2;
  gemm_core<0>(A, B, bias, nullptr, O, 1024, 1024, blockIdx.x * 128, blockIdx.y * 128);
}

// ---------------- flash attention (no pre-scale, /8 after PV) --------------
// grid: (16 q-tiles, B*H=32), 256 thr (4 waves x 32 q-rows), KVBLK=64
__global__ __launch_bounds__(256) void k_attn(const u16* __restrict__ Q,
                                              const u16* __restrict__ K,
                                              const u16* __restrict__ V,
                                              u16* __restrict__ Z) {
  const int qt = blockIdx.x;
  const int bh = blockIdx.y;
  const int b = bh >> 4, h = bh & 15;
  const int tid = threadIdx.x;
  const int w = tid >> 6, l = tid & 63;
  const int lr = l & 15, lg = l >> 4;

  __shared__ u16 VT[64][64];       // V^T tile, XOR-swizzled (8 KB)
  __shared__ u16 PL[4][32 * 64];   // per-wave P, XOR-swizzled (16 KB)

  const size_t rb = (size_t)b * 2048;
  const int c0 = h * 64;
  const int q0 = qt * 128 + w * 32;

  bf16x8 qa[2][2];
#pragma unroll
  for (int mf = 0; mf < 2; ++mf)
#pragma unroll
    for (int kf = 0; kf < 2; ++kf)
      qa[mf][kf] = *(const bf16x8*)(Q + (rb + q0 + mf * 16 + lr) * 1024 + c0 + kf * 32 + lg * 8);

  f32x4 zacc[2][4] = {};
  float mrun[2][4], lrun[2][4];
#pragma unroll
  for (int mf = 0; mf < 2; ++mf)
#pragma unroll
    for (int r = 0; r < 4; ++r) { mrun[mf][r] = -1e30f; lrun[mf][r] = 0.f; }

  const int vp = tid & 31, vd0 = (tid >> 5) * 8;

  for (int t = 0; t < 32; ++t) {
    const int kv0 = t * 64;
    __syncthreads();  // prior PV reads done before re-staging VT
    {  // stage V^T (pack kv-pairs into b32, swizzle kv by dh bits 2-3)
      const u16* v0 = V + (rb + kv0 + 2 * vp) * 1024 + c0 + vd0;
      u16x8 a0 = *(const u16x8*)v0;
      u16x8 a1 = *(const u16x8*)(v0 + 1024);
#pragma unroll
      for (int i = 0; i < 8; ++i) {
        const int dh = vd0 + i;
        const int kvs = (2 * vp) ^ (((dh >> 2) & 3) << 4);
        uint32_t pk = (uint32_t)a0[i] | ((uint32_t)a1[i] << 16);
        *(uint32_t*)&VT[dh][kvs] = pk;
      }
    }
    // QK^T (K fragments straight from global/L2)
    f32x4 s[2][4] = {};
#pragma unroll
    for (int kf = 0; kf < 2; ++kf) {
      bf16x8 kb[4];
#pragma unroll
      for (int nf = 0; nf < 4; ++nf)
        kb[nf] = *(const bf16x8*)(K + (rb + kv0 + nf * 16 + lr) * 1024 + c0 + kf * 32 + lg * 8);
#pragma unroll
      for (int mf = 0; mf < 2; ++mf)
#pragma unroll
        for (int nf = 0; nf < 4; ++nf)
          s[mf][nf] = __builtin_amdgcn_mfma_f32_16x16x32_bf16(qa[mf][kf], kb[nf], s[mf][nf], 0, 0, 0);
    }
    // online softmax + write P to swizzled LDS
#pragma unroll
    for (int mf = 0; mf < 2; ++mf) {
      f32x4 tm = s[mf][0];
#pragma unroll
      for (int nf = 1; nf < 4; ++nf)
#pragma unroll
        for (int r = 0; r < 4; ++r) tm[r] = fmaxf(tm[r], s[mf][nf][r]);
#pragma unroll
      for (int st = 1; st < 16; st <<= 1)
#pragma unroll
        for (int r = 0; r < 4; ++r) tm[r] = fmaxf(tm[r], __shfl_xor(tm[r], st, 64));
      float sc[4];
#pragma unroll
      for (int r = 0; r < 4; ++r) {
        float mn = fmaxf(mrun[mf][r], tm[r]);
        sc[r] = __expf(mrun[mf][r] - mn);
        mrun[mf][r] = mn;
        lrun[mf][r] *= sc[r];
      }
#pragma unroll
      for (int nf = 0; nf < 4; ++nf)
#pragma unroll
        for (int r = 0; r < 4; ++r) zacc[mf][nf][r] *= sc[r];
#pragma unroll
      for (int nf = 0; nf < 4; ++nf)
#pragma unroll
        for (int r = 0; r < 4; ++r) {
          float p = __expf(s[mf][nf][r] - mrun[mf][r]);
          lrun[mf][r] += p;
          const int q = mf * 16 + lg * 4 + r;
          const int kv = (nf * 16 + lr) ^ (((q >> 2) & 3) << 4);
          PL[w][q * 64 + kv] = f2bf(p);
        }
    }
    __syncthreads();  // VT + P visible
    // PV
#pragma unroll
    for (int kf2 = 0; kf2 < 2; ++kf2) {
      bf16x8 pa[2], vb[4];
#pragma unroll
      for (int mf = 0; mf < 2; ++mf) {
        const int kvb = (kf2 * 32 + lg * 8) ^ (((lr >> 2) & 3) << 4);
        pa[mf] = *(const bf16x8*)&PL[w][(mf * 16 + lr) * 64 + kvb];
      }
#pragma unroll
      for (int nf = 0; nf < 4; ++nf) {
        const int dh = nf * 16 + lr;
        const int kvb = (kf2 * 32 + lg * 8) ^ (((dh >> 2) & 3) << 4);
        vb[nf] = *(const bf16x8*)&VT[dh][kvb];
      }
#pragma unroll
      for (int mf = 0; mf < 2; ++mf)
#pragma unroll
        for (int nf = 0; nf < 4; ++nf)
          zacc[mf][nf] = __builtin_amdgcn_mfma_f32_16x16x32_bf16(pa[mf], vb[nf], zacc[mf][nf], 0, 0, 0);
    }
  }

  // FIX (round 1): softmax denominator. lrun[mf][r] held only this lane's
  // partial sum (kv = nf*16 + lr); the full row sum lives across the 16-lane
  // lr group. mrun is group-uniform (tm was shfl-reduced), so the partials
  // are consistently scaled and a butterfly sum over the lr bits completes l.
#pragma unroll
  for (int mf = 0; mf < 2; ++mf)
#pragma unroll
    for (int st = 1; st < 16; st <<= 1)
#pragma unroll
      for (int r = 0; r < 4; ++r)
        lrun[mf][r] += __shfl_xor(lrun[mf][r], st, 64);

#pragma unroll
  for (int mf = 0; mf < 2; ++mf)
#pragma unroll
    for (int r = 0; r < 4; ++r) {
      const float inv = 0.125f / lrun[mf][r];  // /sqrt(64) folded in
      const size_t row = rb + q0 + mf * 16 + lg * 4 + r;
#pragma unroll
      for (int nf = 0; nf < 4; ++nf)
        Z[row * 1024 + c0 + nf * 16 + lr] = f2bf(zacc[mf][nf][r] * inv);
    }
}

// ---------------- row LayerNorm (1024 cols) ----------------
template <bool WBF>
__global__ __launch_bounds__(256) void k_ln(const float* __restrict__ x,
                                            const float* __restrict__ g,
                                            const float* __restrict__ be,
                                            float* __restrict__ of,
                                            u16* __restrict__ ob) {
  const int row = blockIdx.x;
  const int tid = threadIdx.x;
  const float* xr = x + (size_t)row * 1024;
  float4 v = *(const float4*)(xr + tid * 4);
  float s = v.x + v.y + v.z + v.w;
  float s2 = v.x * v.x + v.y * v.y + v.z * v.z + v.w * v.w;
#pragma unroll
  for (int st = 1; st < 64; st <<= 1) {
    s += __shfl_xor(s, st, 64);
    s2 += __shfl_xor(s2, st, 64);
  }
  __shared__ float ps[8];
  if ((tid & 63) == 0) { ps[tid >> 6] = s; ps[4 + (tid >> 6)] = s2; }
  __syncthreads();
  s = ps[0] + ps[1] + ps[2] + ps[3];
  s2 = ps[4] + ps[5] + ps[6] + ps[7];
  const float mu = s * 0.0009765625f;
  const float var = s2 * 0.0009765625f - mu * mu;
  const float rs = rsqrtf(var + 1e-5f);
  float4 gg = *(const float4*)(g + tid * 4);
  float4 bb = *(const float4*)(be + tid * 4);
  float4 o;
  o.x = (v.x - mu) * rs * gg.x + bb.x;
  o.y = (v.y - mu) * rs * gg.y + bb.y;
  o.z = (v.z - mu) * rs * gg.z + bb.z;
  o.w = (v.w - mu) * rs * gg.w + bb.w;
  *(float4*)(of + (size_t)row * 1024 + tid * 4) = o;
  if (WBF) {
    u16x4 q;
    q[0] = f2bf(o.x); q[1] = f2bf(o.y); q[2] = f2bf(o.z); q[3] = f2bf(o.w);
    *(u16x4*)(ob + (size_t)row * 1024 + tid * 4) = q;
  }
}

// ---------------- launch ----------------
extern "C" void kernel_launch(void* const* d_in, const int* in_sizes, int n_in,
                              void* d_out, int out_size, void* d_ws, size_t ws_size,
                              hipStream_t stream) {
  const float* emb = (const float*)d_in[0];
  const float* Wq  = (const float*)d_in[1];
  const float* bq  = (const float*)d_in[2];
  const float* Wk  = (const float*)d_in[3];
  const float* bk  = (const float*)d_in[4];
  const float* Wv  = (const float*)d_in[5];
  const float* bv  = (const float*)d_in[6];
  const float* W0  = (const float*)d_in[7];
  const float* b0  = (const float*)d_in[8];
  const float* g1  = (const float*)d_in[9];
  const float* be1 = (const float*)d_in[10];
  const float* W1  = (const float*)d_in[11];
  const float* b1  = (const float*)d_in[12];
  const float* W2  = (const float*)d_in[13];
  const float* b2  = (const float*)d_in[14];
  const float* g2  = (const float*)d_in[15];
  const float* be2 = (const float*)d_in[16];

  char* p = (char*)d_ws;
  auto alloc = [&](size_t bytes) { char* r = p; p += bytes; return r; };
  u16* embb = (u16*)alloc(8u << 20);
  u16* Wqb  = (u16*)alloc(2u << 20);
  u16* Wkb  = (u16*)alloc(2u << 20);
  u16* Wvb  = (u16*)alloc(2u << 20);
  u16* W0b  = (u16*)alloc(2u << 20);
  u16* W1b  = (u16*)alloc(8u << 20);
  u16* W2b  = (u16*)alloc(8u << 20);
  u16* Qb   = (u16*)alloc(8u << 20);
  u16* Kb   = (u16*)alloc(8u << 20);
  u16* Vb   = (u16*)alloc(8u << 20);
  u16* Zb   = (u16*)alloc(8u << 20);
  float* y1 = (float*)alloc(16u << 20);   // reused as y2 later
  float* o1f = (float*)alloc(16u << 20);
  u16* o1b  = (u16*)alloc(8u << 20);
  u16* hb   = (u16*)alloc(32u << 20);

  auto cvt = [&](const float* s, u16* d, int n) {
    int blk = (n / 4 + 255) / 256;
    if (blk > 4096) blk = 4096;
    k_cvt<<<blk, 256, 0, stream>>>(s, d, n);
  };
  cvt(emb, embb, 4096 * 1024);
  cvt(Wq, Wqb, 1024 * 1024);
  cvt(Wk, Wkb, 1024 * 1024);
  cvt(Wv, Wvb, 1024 * 1024);
  cvt(W0, W0b, 1024 * 1024);
  cvt(W1, W1b, 4096 * 1024);
  cvt(W2, W2b, 4096 * 1024);

  k_gemm_qkv<<<dim3(32, 8, 3), 256, 0, stream>>>(embb, Wqb, Wkb, Wvb, bq, bk, bv,
                                                 Qb, Kb, Vb);
  k_attn<<<dim3(16, 32), 256, 0, stream>>>(Qb, Kb, Vb, Zb);
  // y1 = Z @ W0^T + b0 + emb
  k_gemm<2><<<dim3(32, 8), 256, 0, stream>>>(Zb, W0b, b0, emb, y1, 1024, 1024);
  k_ln<true><<<4096, 256, 0, stream>>>(y1, g1, be1, o1f, o1b);
  // h = relu(out1 @ W1^T + b1)
  k_gemm<1><<<dim3(32, 32), 256, 0, stream>>>(o1b, W1b, b1, nullptr, hb, 4096, 1024);
  // y2 = h @ W2^T + b2 + out1   (reuse y1 buffer)
  k_gemm<2><<<dim3(32, 8), 256, 0, stream>>>(hb, W2b, b2, o1f, y1, 1024, 4096);
  k_ln<false><<<4096, 256, 0, stream>>>(y1, g2, be2, (float*)d_out, nullptr);
}